// Round 2
// baseline (202.901 us; speedup 1.0000x reference)
//
#include <hip/hip_runtime.h>

// IoU mean over B=1e6 x NBOX=6 midpoint-format box pairs, sentinel-masked.
// Streaming reduction: 192 MB logical in, 1 float out. R0 showed
// latency-bound (Occ 39%, VALUBusy 10%, HBM 18%): grid capped waves at 50%
// and loop had low MLP. R1: full-occupancy grid (2048x256 = 8192 waves) +
// unroll-by-4 with 8 independent float4 loads in flight per iteration.

#define BLOCKS 2048
#define THREADS 256

__device__ __forceinline__ void iou_accum(float4 p, float4 t,
                                          float& s_iou, float& s_cnt) {
    // valid iff truth row is not the sentinel [-1,-1,-1,-1]; branchless mask
    float v = (t.x == -1.0f && t.y == -1.0f &&
               t.z == -1.0f && t.w == -1.0f) ? 0.0f : 1.0f;

    float p_x1 = p.x - p.z * 0.5f;
    float p_y1 = p.y - p.w * 0.5f;
    float p_x2 = p.x + p.z * 0.5f;
    float p_y2 = p.y + p.w * 0.5f;
    float t_x1 = t.x - t.z * 0.5f;
    float t_y1 = t.y - t.w * 0.5f;
    float t_x2 = t.x + t.z * 0.5f;
    float t_y2 = t.y + t.w * 0.5f;

    float x1 = fmaxf(p_x1, t_x1);
    float y1 = fmaxf(p_y1, t_y1);
    float x2 = fminf(p_x2, t_x2);
    float y2 = fminf(p_y2, t_y2);

    float inter  = fmaxf(x2 - x1, 0.0f) * fmaxf(y2 - y1, 0.0f);
    float area_p = fabsf((p_x2 - p_x1) * (p_y2 - p_y1));
    float area_t = fabsf((t_x2 - t_x1) * (t_y2 - t_y1));

    s_iou += v * (inter / (area_p + area_t - inter + 1e-6f));
    s_cnt += v;
}

__global__ __launch_bounds__(THREADS) void iou_partial(
    const float4* __restrict__ pred,
    const float4* __restrict__ truth,
    float* __restrict__ partials,   // [BLOCKS][2]: {sum_iou, sum_valid}
    int n)                          // number of (b,box) pairs
{
    int tid = blockIdx.x * THREADS + threadIdx.x;
    const int stride = BLOCKS * THREADS;

    float s_iou = 0.0f;
    float s_cnt = 0.0f;

    int i = tid;
    // unrolled x4: issue all 8 loads before any compute (MLP)
    for (; i + 3 * stride < n; i += 4 * stride) {
        float4 p0 = pred[i];
        float4 p1 = pred[i + stride];
        float4 p2 = pred[i + 2 * stride];
        float4 p3 = pred[i + 3 * stride];
        float4 t0 = truth[i];
        float4 t1 = truth[i + stride];
        float4 t2 = truth[i + 2 * stride];
        float4 t3 = truth[i + 3 * stride];
        iou_accum(p0, t0, s_iou, s_cnt);
        iou_accum(p1, t1, s_iou, s_cnt);
        iou_accum(p2, t2, s_iou, s_cnt);
        iou_accum(p3, t3, s_iou, s_cnt);
    }
    for (; i < n; i += stride) {
        float4 p = pred[i];
        float4 t = truth[i];
        iou_accum(p, t, s_iou, s_cnt);
    }

    // wave (64-lane) shuffle reduction
    for (int off = 32; off > 0; off >>= 1) {
        s_iou += __shfl_down(s_iou, off, 64);
        s_cnt += __shfl_down(s_cnt, off, 64);
    }

    __shared__ float lds_iou[THREADS / 64];
    __shared__ float lds_cnt[THREADS / 64];
    int lane = threadIdx.x & 63;
    int wave = threadIdx.x >> 6;
    if (lane == 0) {
        lds_iou[wave] = s_iou;
        lds_cnt[wave] = s_cnt;
    }
    __syncthreads();

    if (threadIdx.x == 0) {
        float a = 0.0f, b = 0.0f;
        #pragma unroll
        for (int w = 0; w < THREADS / 64; ++w) {
            a += lds_iou[w];
            b += lds_cnt[w];
        }
        partials[2 * blockIdx.x]     = a;
        partials[2 * blockIdx.x + 1] = b;
    }
}

__global__ __launch_bounds__(THREADS) void iou_finalize(
    const float* __restrict__ partials, int nblocks, float* __restrict__ out)
{
    float s_iou = 0.0f;
    float s_cnt = 0.0f;
    for (int i = threadIdx.x; i < nblocks; i += blockDim.x) {
        s_iou += partials[2 * i];
        s_cnt += partials[2 * i + 1];
    }
    for (int off = 32; off > 0; off >>= 1) {
        s_iou += __shfl_down(s_iou, off, 64);
        s_cnt += __shfl_down(s_cnt, off, 64);
    }
    __shared__ float lds_iou[THREADS / 64];
    __shared__ float lds_cnt[THREADS / 64];
    int lane = threadIdx.x & 63;
    int wave = threadIdx.x >> 6;
    if (lane == 0) {
        lds_iou[wave] = s_iou;
        lds_cnt[wave] = s_cnt;
    }
    __syncthreads();
    if (threadIdx.x == 0) {
        float a = 0.0f, b = 0.0f;
        #pragma unroll
        for (int w = 0; w < THREADS / 64; ++w) {
            a += lds_iou[w];
            b += lds_cnt[w];
        }
        out[0] = (b > 0.0f) ? (a / fmaxf(b, 1.0f)) : 0.0f;
    }
}

extern "C" void kernel_launch(void* const* d_in, const int* in_sizes, int n_in,
                              void* d_out, int out_size, void* d_ws, size_t ws_size,
                              hipStream_t stream) {
    const float4* pred  = (const float4*)d_in[0];
    const float4* truth = (const float4*)d_in[1];
    float* out = (float*)d_out;
    float* partials = (float*)d_ws;   // BLOCKS*2 floats, overwritten every call

    int n_pairs = in_sizes[0] / 4;    // B * NBOX

    iou_partial<<<BLOCKS, THREADS, 0, stream>>>(pred, truth, partials, n_pairs);
    iou_finalize<<<1, THREADS, 0, stream>>>(partials, BLOCKS, out);
}

// Round 4
// 194.000 us; speedup vs baseline: 1.0459x; 1.0459x over previous
//
#include <hip/hip_runtime.h>

// IoU mean over B=1e6 x NBOX=6 midpoint-format box pairs, sentinel-masked.
// Streaming reduction: 192 MB logical in, 1 float out.
// R0 (1024 blk, 2 loads in flight): 66.6 us, 1.44 TB/s HBM.
// R1 (2048 blk = 100% wave slots, 8 loads in flight): 68.0 us, 1.40 TB/s.
//   -> BW wall at ~2.8 TB/s combined (HBM+L3) is INSENSITIVE to occupancy
//      and MLP; not VALU (13.5% busy), not LDS, not divergence.
// R2/R3: test cache-allocation-policy hypothesis with nontemporal loads
//     (global_load_dwordx4 nt). R3 fixes the builtin's type requirement:
//     it needs a native clang vector type, not HIP_vector_type.

#define BLOCKS 2048
#define THREADS 256

typedef float vfloat4 __attribute__((ext_vector_type(4)));

__device__ __forceinline__ vfloat4 nt_load4(const float4* p) {
    return __builtin_nontemporal_load((const vfloat4*)p);
}

__device__ __forceinline__ void iou_accum(vfloat4 p, vfloat4 t,
                                          float& s_iou, float& s_cnt) {
    // valid iff truth row is not the sentinel [-1,-1,-1,-1]; branchless mask
    float v = (t.x == -1.0f && t.y == -1.0f &&
               t.z == -1.0f && t.w == -1.0f) ? 0.0f : 1.0f;

    float p_x1 = p.x - p.z * 0.5f;
    float p_y1 = p.y - p.w * 0.5f;
    float p_x2 = p.x + p.z * 0.5f;
    float p_y2 = p.y + p.w * 0.5f;
    float t_x1 = t.x - t.z * 0.5f;
    float t_y1 = t.y - t.w * 0.5f;
    float t_x2 = t.x + t.z * 0.5f;
    float t_y2 = t.y + t.w * 0.5f;

    float x1 = fmaxf(p_x1, t_x1);
    float y1 = fmaxf(p_y1, t_y1);
    float x2 = fminf(p_x2, t_x2);
    float y2 = fminf(p_y2, t_y2);

    float inter  = fmaxf(x2 - x1, 0.0f) * fmaxf(y2 - y1, 0.0f);
    float area_p = fabsf((p_x2 - p_x1) * (p_y2 - p_y1));
    float area_t = fabsf((t_x2 - t_x1) * (t_y2 - t_y1));

    s_iou += v * (inter / (area_p + area_t - inter + 1e-6f));
    s_cnt += v;
}

__global__ __launch_bounds__(THREADS) void iou_partial(
    const float4* __restrict__ pred,
    const float4* __restrict__ truth,
    float* __restrict__ partials,   // [BLOCKS][2]: {sum_iou, sum_valid}
    int n)                          // number of (b,box) pairs
{
    int tid = blockIdx.x * THREADS + threadIdx.x;
    const int stride = BLOCKS * THREADS;

    float s_iou = 0.0f;
    float s_cnt = 0.0f;

    int i = tid;
    // unrolled x4: issue all 8 loads before any compute (MLP)
    for (; i + 3 * stride < n; i += 4 * stride) {
        vfloat4 p0 = nt_load4(&pred[i]);
        vfloat4 p1 = nt_load4(&pred[i + stride]);
        vfloat4 p2 = nt_load4(&pred[i + 2 * stride]);
        vfloat4 p3 = nt_load4(&pred[i + 3 * stride]);
        vfloat4 t0 = nt_load4(&truth[i]);
        vfloat4 t1 = nt_load4(&truth[i + stride]);
        vfloat4 t2 = nt_load4(&truth[i + 2 * stride]);
        vfloat4 t3 = nt_load4(&truth[i + 3 * stride]);
        iou_accum(p0, t0, s_iou, s_cnt);
        iou_accum(p1, t1, s_iou, s_cnt);
        iou_accum(p2, t2, s_iou, s_cnt);
        iou_accum(p3, t3, s_iou, s_cnt);
    }
    for (; i < n; i += stride) {
        vfloat4 p = nt_load4(&pred[i]);
        vfloat4 t = nt_load4(&truth[i]);
        iou_accum(p, t, s_iou, s_cnt);
    }

    // wave (64-lane) shuffle reduction
    for (int off = 32; off > 0; off >>= 1) {
        s_iou += __shfl_down(s_iou, off, 64);
        s_cnt += __shfl_down(s_cnt, off, 64);
    }

    __shared__ float lds_iou[THREADS / 64];
    __shared__ float lds_cnt[THREADS / 64];
    int lane = threadIdx.x & 63;
    int wave = threadIdx.x >> 6;
    if (lane == 0) {
        lds_iou[wave] = s_iou;
        lds_cnt[wave] = s_cnt;
    }
    __syncthreads();

    if (threadIdx.x == 0) {
        float a = 0.0f, b = 0.0f;
        #pragma unroll
        for (int w = 0; w < THREADS / 64; ++w) {
            a += lds_iou[w];
            b += lds_cnt[w];
        }
        partials[2 * blockIdx.x]     = a;
        partials[2 * blockIdx.x + 1] = b;
    }
}

__global__ __launch_bounds__(THREADS) void iou_finalize(
    const float* __restrict__ partials, int nblocks, float* __restrict__ out)
{
    float s_iou = 0.0f;
    float s_cnt = 0.0f;
    for (int i = threadIdx.x; i < nblocks; i += blockDim.x) {
        s_iou += partials[2 * i];
        s_cnt += partials[2 * i + 1];
    }
    for (int off = 32; off > 0; off >>= 1) {
        s_iou += __shfl_down(s_iou, off, 64);
        s_cnt += __shfl_down(s_cnt, off, 64);
    }
    __shared__ float lds_iou[THREADS / 64];
    __shared__ float lds_cnt[THREADS / 64];
    int lane = threadIdx.x & 63;
    int wave = threadIdx.x >> 6;
    if (lane == 0) {
        lds_iou[wave] = s_iou;
        lds_cnt[wave] = s_cnt;
    }
    __syncthreads();
    if (threadIdx.x == 0) {
        float a = 0.0f, b = 0.0f;
        #pragma unroll
        for (int w = 0; w < THREADS / 64; ++w) {
            a += lds_iou[w];
            b += lds_cnt[w];
        }
        out[0] = (b > 0.0f) ? (a / fmaxf(b, 1.0f)) : 0.0f;
    }
}

extern "C" void kernel_launch(void* const* d_in, const int* in_sizes, int n_in,
                              void* d_out, int out_size, void* d_ws, size_t ws_size,
                              hipStream_t stream) {
    const float4* pred  = (const float4*)d_in[0];
    const float4* truth = (const float4*)d_in[1];
    float* out = (float*)d_out;
    float* partials = (float*)d_ws;   // BLOCKS*2 floats, overwritten every call

    int n_pairs = in_sizes[0] / 4;    // B * NBOX

    iou_partial<<<BLOCKS, THREADS, 0, stream>>>(pred, truth, partials, n_pairs);
    iou_finalize<<<1, THREADS, 0, stream>>>(partials, BLOCKS, out);
}

// Round 5
// 189.942 us; speedup vs baseline: 1.0682x; 1.0214x over previous
//
#include <hip/hip_runtime.h>

// IoU mean over B=1e6 x NBOX=6 midpoint-format box pairs, sentinel-masked.
// Streaming reduction: 192 MB logical in, 1 float out.
// R0: 1024 blk, MLP=2            -> iou_partial 66.6 us, 1.44 TB/s HBM
// R1: 2048 blk (100% waves), MLP=8 -> 68.0 us. BW wall insensitive to occ/MLP.
// R3: nontemporal loads (dwordx4 nt) -> iou_partial < 56 us (left top-5);
//     harness fills show platform sustains 6.7 TB/s, so the old wall was
//     cache-allocation policy, not DRAM. Total now dominated by ~140 us of
//     harness restore (384 MB ws poison @57us + 192 MB input restore).
// R4: kill the tail: 1953 blk x 256 = 499968 threads x exactly 12 pairs;
//     unroll-6 (12 nt loads in flight), split accumulators to break the
//     divide->add serial chain. Target iou_partial ~40 us (floor ~28).

#define BLOCKS 1953
#define THREADS 256

typedef float vfloat4 __attribute__((ext_vector_type(4)));

__device__ __forceinline__ vfloat4 nt_load4(const float4* p) {
    return __builtin_nontemporal_load((const vfloat4*)p);
}

__device__ __forceinline__ void iou_accum(vfloat4 p, vfloat4 t,
                                          float& s_iou, float& s_cnt) {
    // valid iff truth row is not the sentinel [-1,-1,-1,-1]; branchless mask
    float v = (t.x == -1.0f && t.y == -1.0f &&
               t.z == -1.0f && t.w == -1.0f) ? 0.0f : 1.0f;

    float p_x1 = p.x - p.z * 0.5f;
    float p_y1 = p.y - p.w * 0.5f;
    float p_x2 = p.x + p.z * 0.5f;
    float p_y2 = p.y + p.w * 0.5f;
    float t_x1 = t.x - t.z * 0.5f;
    float t_y1 = t.y - t.w * 0.5f;
    float t_x2 = t.x + t.z * 0.5f;
    float t_y2 = t.y + t.w * 0.5f;

    float x1 = fmaxf(p_x1, t_x1);
    float y1 = fmaxf(p_y1, t_y1);
    float x2 = fminf(p_x2, t_x2);
    float y2 = fminf(p_y2, t_y2);

    float inter  = fmaxf(x2 - x1, 0.0f) * fmaxf(y2 - y1, 0.0f);
    float area_p = fabsf((p_x2 - p_x1) * (p_y2 - p_y1));
    float area_t = fabsf((t_x2 - t_x1) * (t_y2 - t_y1));

    s_iou += v * (inter / (area_p + area_t - inter + 1e-6f));
    s_cnt += v;
}

__global__ __launch_bounds__(THREADS) void iou_partial(
    const float4* __restrict__ pred,
    const float4* __restrict__ truth,
    float* __restrict__ partials,   // [BLOCKS][2]: {sum_iou, sum_valid}
    int n)                          // number of (b,box) pairs
{
    int tid = blockIdx.x * THREADS + threadIdx.x;
    const int stride = BLOCKS * THREADS;

    // two independent accumulator pairs to break the divide->add chain
    float s_iou0 = 0.0f, s_cnt0 = 0.0f;
    float s_iou1 = 0.0f, s_cnt1 = 0.0f;

    int i = tid;
    // unroll x6: 12 independent nt loads in flight before any compute
    for (; i + 5 * stride < n; i += 6 * stride) {
        vfloat4 p0 = nt_load4(&pred[i]);
        vfloat4 p1 = nt_load4(&pred[i + stride]);
        vfloat4 p2 = nt_load4(&pred[i + 2 * stride]);
        vfloat4 p3 = nt_load4(&pred[i + 3 * stride]);
        vfloat4 p4 = nt_load4(&pred[i + 4 * stride]);
        vfloat4 p5 = nt_load4(&pred[i + 5 * stride]);
        vfloat4 t0 = nt_load4(&truth[i]);
        vfloat4 t1 = nt_load4(&truth[i + stride]);
        vfloat4 t2 = nt_load4(&truth[i + 2 * stride]);
        vfloat4 t3 = nt_load4(&truth[i + 3 * stride]);
        vfloat4 t4 = nt_load4(&truth[i + 4 * stride]);
        vfloat4 t5 = nt_load4(&truth[i + 5 * stride]);
        iou_accum(p0, t0, s_iou0, s_cnt0);
        iou_accum(p1, t1, s_iou1, s_cnt1);
        iou_accum(p2, t2, s_iou0, s_cnt0);
        iou_accum(p3, t3, s_iou1, s_cnt1);
        iou_accum(p4, t4, s_iou0, s_cnt0);
        iou_accum(p5, t5, s_iou1, s_cnt1);
    }
    for (; i < n; i += stride) {
        vfloat4 p = nt_load4(&pred[i]);
        vfloat4 t = nt_load4(&truth[i]);
        iou_accum(p, t, s_iou0, s_cnt0);
    }

    float s_iou = s_iou0 + s_iou1;
    float s_cnt = s_cnt0 + s_cnt1;

    // wave (64-lane) shuffle reduction
    for (int off = 32; off > 0; off >>= 1) {
        s_iou += __shfl_down(s_iou, off, 64);
        s_cnt += __shfl_down(s_cnt, off, 64);
    }

    __shared__ float lds_iou[THREADS / 64];
    __shared__ float lds_cnt[THREADS / 64];
    int lane = threadIdx.x & 63;
    int wave = threadIdx.x >> 6;
    if (lane == 0) {
        lds_iou[wave] = s_iou;
        lds_cnt[wave] = s_cnt;
    }
    __syncthreads();

    if (threadIdx.x == 0) {
        float a = 0.0f, b = 0.0f;
        #pragma unroll
        for (int w = 0; w < THREADS / 64; ++w) {
            a += lds_iou[w];
            b += lds_cnt[w];
        }
        partials[2 * blockIdx.x]     = a;
        partials[2 * blockIdx.x + 1] = b;
    }
}

__global__ __launch_bounds__(THREADS) void iou_finalize(
    const float* __restrict__ partials, int nblocks, float* __restrict__ out)
{
    float s_iou = 0.0f;
    float s_cnt = 0.0f;
    for (int i = threadIdx.x; i < nblocks; i += blockDim.x) {
        s_iou += partials[2 * i];
        s_cnt += partials[2 * i + 1];
    }
    for (int off = 32; off > 0; off >>= 1) {
        s_iou += __shfl_down(s_iou, off, 64);
        s_cnt += __shfl_down(s_cnt, off, 64);
    }
    __shared__ float lds_iou[THREADS / 64];
    __shared__ float lds_cnt[THREADS / 64];
    int lane = threadIdx.x & 63;
    int wave = threadIdx.x >> 6;
    if (lane == 0) {
        lds_iou[wave] = s_iou;
        lds_cnt[wave] = s_cnt;
    }
    __syncthreads();
    if (threadIdx.x == 0) {
        float a = 0.0f, b = 0.0f;
        #pragma unroll
        for (int w = 0; w < THREADS / 64; ++w) {
            a += lds_iou[w];
            b += lds_cnt[w];
        }
        out[0] = (b > 0.0f) ? (a / fmaxf(b, 1.0f)) : 0.0f;
    }
}

extern "C" void kernel_launch(void* const* d_in, const int* in_sizes, int n_in,
                              void* d_out, int out_size, void* d_ws, size_t ws_size,
                              hipStream_t stream) {
    const float4* pred  = (const float4*)d_in[0];
    const float4* truth = (const float4*)d_in[1];
    float* out = (float*)d_out;
    float* partials = (float*)d_ws;   // BLOCKS*2 floats, overwritten every call

    int n_pairs = in_sizes[0] / 4;    // B * NBOX

    iou_partial<<<BLOCKS, THREADS, 0, stream>>>(pred, truth, partials, n_pairs);
    iou_finalize<<<1, THREADS, 0, stream>>>(partials, BLOCKS, out);
}

// Round 6
// 189.651 us; speedup vs baseline: 1.0699x; 1.0015x over previous
//
#include <hip/hip_runtime.h>

// IoU mean over B=1e6 x NBOX=6 midpoint-format box pairs, sentinel-masked.
// Streaming reduction: 192 MB logical in, 1 float out.
// R0: 1024 blk, MLP=2              -> iou_partial 66.6 us, 1.44 TB/s HBM
// R1: 2048 blk (100% waves), MLP=8 -> 68.0 us. Wall insensitive to occ/MLP.
// R3: nontemporal loads (dwordx4 nt) -> iou_partial < 56 us (left top-5);
//     harness fills sustain 6.8 TB/s -> old wall was cache-allocation
//     policy, not DRAM. Total now dominated by harness restore traffic.
// R4: exact-cover grid (1953 blk x 256 x 12 pairs), unroll-6, split
//     accumulators -> 194 -> 190 us total.
// R5: replace IEEE fdiv (v_div_scale/fmas/fixup, ~10 VALU + long chain per
//     pair) with v_rcp_f32 + mul (~1e-7 rel err vs 1.3e-3 threshold).
//     Last VALU lever; if neutral, kernel is at streaming equilibrium.

#define BLOCKS 1953
#define THREADS 256

typedef float vfloat4 __attribute__((ext_vector_type(4)));

__device__ __forceinline__ vfloat4 nt_load4(const float4* p) {
    return __builtin_nontemporal_load((const vfloat4*)p);
}

__device__ __forceinline__ void iou_accum(vfloat4 p, vfloat4 t,
                                          float& s_iou, float& s_cnt) {
    // valid iff truth row is not the sentinel [-1,-1,-1,-1]; branchless mask
    float v = (t.x == -1.0f && t.y == -1.0f &&
               t.z == -1.0f && t.w == -1.0f) ? 0.0f : 1.0f;

    float p_x1 = p.x - p.z * 0.5f;
    float p_y1 = p.y - p.w * 0.5f;
    float p_x2 = p.x + p.z * 0.5f;
    float p_y2 = p.y + p.w * 0.5f;
    float t_x1 = t.x - t.z * 0.5f;
    float t_y1 = t.y - t.w * 0.5f;
    float t_x2 = t.x + t.z * 0.5f;
    float t_y2 = t.y + t.w * 0.5f;

    float x1 = fmaxf(p_x1, t_x1);
    float y1 = fmaxf(p_y1, t_y1);
    float x2 = fminf(p_x2, t_x2);
    float y2 = fminf(p_y2, t_y2);

    float inter  = fmaxf(x2 - x1, 0.0f) * fmaxf(y2 - y1, 0.0f);
    float area_p = fabsf((p_x2 - p_x1) * (p_y2 - p_y1));
    float area_t = fabsf((t_x2 - t_x1) * (t_y2 - t_y1));

    // fast reciprocal: v_rcp_f32 (rel err ~1e-7) instead of IEEE fdiv
    float denom = area_p + area_t - inter + 1e-6f;
    s_iou += v * inter * __builtin_amdgcn_rcpf(denom);
    s_cnt += v;
}

__global__ __launch_bounds__(THREADS) void iou_partial(
    const float4* __restrict__ pred,
    const float4* __restrict__ truth,
    float* __restrict__ partials,   // [BLOCKS][2]: {sum_iou, sum_valid}
    int n)                          // number of (b,box) pairs
{
    int tid = blockIdx.x * THREADS + threadIdx.x;
    const int stride = BLOCKS * THREADS;

    // two independent accumulator pairs to break the rcp->add serial chain
    float s_iou0 = 0.0f, s_cnt0 = 0.0f;
    float s_iou1 = 0.0f, s_cnt1 = 0.0f;

    int i = tid;
    // unroll x6: 12 independent nt loads in flight before any compute
    for (; i + 5 * stride < n; i += 6 * stride) {
        vfloat4 p0 = nt_load4(&pred[i]);
        vfloat4 p1 = nt_load4(&pred[i + stride]);
        vfloat4 p2 = nt_load4(&pred[i + 2 * stride]);
        vfloat4 p3 = nt_load4(&pred[i + 3 * stride]);
        vfloat4 p4 = nt_load4(&pred[i + 4 * stride]);
        vfloat4 p5 = nt_load4(&pred[i + 5 * stride]);
        vfloat4 t0 = nt_load4(&truth[i]);
        vfloat4 t1 = nt_load4(&truth[i + stride]);
        vfloat4 t2 = nt_load4(&truth[i + 2 * stride]);
        vfloat4 t3 = nt_load4(&truth[i + 3 * stride]);
        vfloat4 t4 = nt_load4(&truth[i + 4 * stride]);
        vfloat4 t5 = nt_load4(&truth[i + 5 * stride]);
        iou_accum(p0, t0, s_iou0, s_cnt0);
        iou_accum(p1, t1, s_iou1, s_cnt1);
        iou_accum(p2, t2, s_iou0, s_cnt0);
        iou_accum(p3, t3, s_iou1, s_cnt1);
        iou_accum(p4, t4, s_iou0, s_cnt0);
        iou_accum(p5, t5, s_iou1, s_cnt1);
    }
    for (; i < n; i += stride) {
        vfloat4 p = nt_load4(&pred[i]);
        vfloat4 t = nt_load4(&truth[i]);
        iou_accum(p, t, s_iou0, s_cnt0);
    }

    float s_iou = s_iou0 + s_iou1;
    float s_cnt = s_cnt0 + s_cnt1;

    // wave (64-lane) shuffle reduction
    for (int off = 32; off > 0; off >>= 1) {
        s_iou += __shfl_down(s_iou, off, 64);
        s_cnt += __shfl_down(s_cnt, off, 64);
    }

    __shared__ float lds_iou[THREADS / 64];
    __shared__ float lds_cnt[THREADS / 64];
    int lane = threadIdx.x & 63;
    int wave = threadIdx.x >> 6;
    if (lane == 0) {
        lds_iou[wave] = s_iou;
        lds_cnt[wave] = s_cnt;
    }
    __syncthreads();

    if (threadIdx.x == 0) {
        float a = 0.0f, b = 0.0f;
        #pragma unroll
        for (int w = 0; w < THREADS / 64; ++w) {
            a += lds_iou[w];
            b += lds_cnt[w];
        }
        partials[2 * blockIdx.x]     = a;
        partials[2 * blockIdx.x + 1] = b;
    }
}

__global__ __launch_bounds__(THREADS) void iou_finalize(
    const float* __restrict__ partials, int nblocks, float* __restrict__ out)
{
    float s_iou = 0.0f;
    float s_cnt = 0.0f;
    for (int i = threadIdx.x; i < nblocks; i += blockDim.x) {
        s_iou += partials[2 * i];
        s_cnt += partials[2 * i + 1];
    }
    for (int off = 32; off > 0; off >>= 1) {
        s_iou += __shfl_down(s_iou, off, 64);
        s_cnt += __shfl_down(s_cnt, off, 64);
    }
    __shared__ float lds_iou[THREADS / 64];
    __shared__ float lds_cnt[THREADS / 64];
    int lane = threadIdx.x & 63;
    int wave = threadIdx.x >> 6;
    if (lane == 0) {
        lds_iou[wave] = s_iou;
        lds_cnt[wave] = s_cnt;
    }
    __syncthreads();
    if (threadIdx.x == 0) {
        float a = 0.0f, b = 0.0f;
        #pragma unroll
        for (int w = 0; w < THREADS / 64; ++w) {
            a += lds_iou[w];
            b += lds_cnt[w];
        }
        // final divide runs once; keep it exact
        out[0] = (b > 0.0f) ? (a / fmaxf(b, 1.0f)) : 0.0f;
    }
}

extern "C" void kernel_launch(void* const* d_in, const int* in_sizes, int n_in,
                              void* d_out, int out_size, void* d_ws, size_t ws_size,
                              hipStream_t stream) {
    const float4* pred  = (const float4*)d_in[0];
    const float4* truth = (const float4*)d_in[1];
    float* out = (float*)d_out;
    float* partials = (float*)d_ws;   // BLOCKS*2 floats, overwritten every call

    int n_pairs = in_sizes[0] / 4;    // B * NBOX

    iou_partial<<<BLOCKS, THREADS, 0, stream>>>(pred, truth, partials, n_pairs);
    iou_finalize<<<1, THREADS, 0, stream>>>(partials, BLOCKS, out);
}